// Round 4
// baseline (141.783 us; speedup 1.0000x reference)
//
#include <hip/hip_runtime.h>

// EuclideanLoss: loss = (1/(B*N)) * sum_{b,n} w_n * sqrt(sum_d (x[b,n,d]-y[b,d,n])^2)
// w_n = 1.5 for n in {1,2}. B=32, N=8192, D=64, fp32. 134 MB moved, zero reuse.
//
// R9: R8 post-mortem — FETCH fix confirmed (101->65.5 MB) but delivered BW pinned
// at 3.2 TB/s with NOTHING saturated (HBM 19%, VALU 3.6%, conflicts 0, occ 39%).
// All burst-mode kernels cluster at 42-49us; the m13 copy probe (steady-state
// grid-stride) hit 6.29 TB/s total traffic on this chip. Remaining structural
// difference: burst-then-die block lifecycle vs steady-state streaming.
// R9 = streaming pipeline: 512 blocks (2/CU), each owns 4 b-tiles (b=by+8t),
// 2-deep register double-buffer (A/B sets), ZERO barriers in the main loop
// (per-tile accumulators in distinct registers, single LDS exchange at the end).
// Compiler emits counted vmcnt -> next tile's 16 loads stay in flight through
// each consume (never-drain pattern). Per-CU sustained in-flight ~200KB.
// Decisive: if this still delivers 3.2 TB/s, the wall is structural -> roofline.
//
// Per-tile mapping (= R8, FETCH-clean): wave w: nh=w>>1, dh=w&1. lane g:
// c=g&15, dw=g>>4. Thread owns n=n0+64nh+4c..+3, d=32dh+8dw..+7.
//   x: 4 rows x 2 float4 -> 16 lines/instr, fully consumed by adjacent instrs.
//   y: 8 rows x 1 float4 -> 4 x 256B contiguous segments per instr.

constexpr int B  = 32;
constexpr int N  = 8192;
constexpr int D  = 64;
constexpr int TN = 128;               // n per block
constexpr int GX = N / TN;            // 64
constexpr int GY = 8;                 // b-blocks; each handles b = by+8t, t=0..3
constexpr int NBLK = B * GX;          // 2048 partials, ws[b*GX + gx]

__global__ __launch_bounds__(256) void euclid_loss_kernel(
    const float* __restrict__ x,   // [B, N, D]
    const float* __restrict__ y,   // [B, D, N]
    float* __restrict__ ws)        // [NBLK]
{
    const int tid = threadIdx.x;
    const int w   = tid >> 6;
    const int g   = tid & 63;
    const int c   = g & 15;            // n-group of 4 within half
    const int dw  = g >> 4;            // d-window (0..3) of 8
    const int nh  = w >> 1;            // n-half
    const int dh  = w & 1;             // d-half
    const int n0  = blockIdx.x * TN;
    const int by  = blockIdx.y;        // 0..7
    const int nb  = n0 + nh * 64 + 4 * c;
    const int d0  = dh * 32 + dw * 8;

    const float* xb = x + ((size_t)by * N + nb) * D + d0;  // 4 rows, stride D
    const float* yb = y + ((size_t)by * D + d0) * N + nb;  // 8 rows, stride N
    constexpr size_t TS = (size_t)GY * N * D;              // b-step: 8*N*D floats

    float4 xrA[4][2], xrB[4][2], yvA[8], yvB[8];
    float  accT[4][4];
#pragma unroll
    for (int t = 0; t < 4; ++t)
#pragma unroll
        for (int r = 0; r < 4; ++r) accT[t][r] = 0.f;

#define LOADT(XR, YV, t)                                                        \
    {                                                                           \
        const float* xpt = xb + (size_t)(t) * TS;                               \
        const float* ypt = yb + (size_t)(t) * TS;                               \
        _Pragma("unroll")                                                       \
        for (int r = 0; r < 4; ++r) {                                           \
            XR[r][0] = *reinterpret_cast<const float4*>(xpt + r * D);           \
            XR[r][1] = *reinterpret_cast<const float4*>(xpt + r * D + 4);       \
        }                                                                       \
        _Pragma("unroll")                                                       \
        for (int jd = 0; jd < 8; ++jd)                                          \
            YV[jd] = *reinterpret_cast<const float4*>(ypt + (size_t)jd * N);    \
    }

#define ACC1(XR, YV, acc, r, CMP)                                               \
    { float t_;                                                                 \
      t_ = XR[r][0].x - YV[0].CMP; acc[r] += t_ * t_;                           \
      t_ = XR[r][0].y - YV[1].CMP; acc[r] += t_ * t_;                           \
      t_ = XR[r][0].z - YV[2].CMP; acc[r] += t_ * t_;                           \
      t_ = XR[r][0].w - YV[3].CMP; acc[r] += t_ * t_;                           \
      t_ = XR[r][1].x - YV[4].CMP; acc[r] += t_ * t_;                           \
      t_ = XR[r][1].y - YV[5].CMP; acc[r] += t_ * t_;                           \
      t_ = XR[r][1].z - YV[6].CMP; acc[r] += t_ * t_;                           \
      t_ = XR[r][1].w - YV[7].CMP; acc[r] += t_ * t_; }

#define CONSUME(XR, YV, acc)                                                    \
    ACC1(XR, YV, acc, 0, x) ACC1(XR, YV, acc, 1, y)                             \
    ACC1(XR, YV, acc, 2, z) ACC1(XR, YV, acc, 3, w)

    // 2-deep software pipeline over 4 b-tiles; no barriers, counted vmcnt only.
    LOADT(xrA, yvA, 0)
    LOADT(xrB, yvB, 1)
    CONSUME(xrA, yvA, accT[0])
    LOADT(xrA, yvA, 2)
    CONSUME(xrB, yvB, accT[1])
    LOADT(xrB, yvB, 3)
    CONSUME(xrA, yvA, accT[2])
    CONSUME(xrB, yvB, accT[3])

#undef LOADT
#undef ACC1
#undef CONSUME

    // Single epilogue: exchange all 4 tiles' partials through 16KB LDS.
    __shared__ float partF[4][2][4][128];   // [t][dh][dw][nh*64 + 4c + r]
#pragma unroll
    for (int t = 0; t < 4; ++t)
        *reinterpret_cast<float4*>(&partF[t][dh][dw][nh * 64 + 4 * c]) =
            make_float4(accT[t][0], accT[t][1], accT[t][2], accT[t][3]);
    __syncthreads();

    float v0 = 0.f, v1 = 0.f, v2 = 0.f, v3 = 0.f;
    if (tid < TN) {                      // finisher: one thread per n
        const int nh2 = tid >> 6;
        const int m   = tid & 63;
        float s0 = 0.f, s1 = 0.f, s2 = 0.f, s3 = 0.f;
#pragma unroll
        for (int dh2 = 0; dh2 < 2; ++dh2)
#pragma unroll
            for (int dw2 = 0; dw2 < 4; ++dw2) {
                s0 += partF[0][dh2][dw2][nh2 * 64 + m];
                s1 += partF[1][dh2][dw2][nh2 * 64 + m];
                s2 += partF[2][dh2][dw2][nh2 * 64 + m];
                s3 += partF[3][dh2][dw2][nh2 * 64 + m];
            }
        const int n = n0 + tid;
        const float wt = (n == 1 || n == 2) ? 1.5f : 1.0f;
        v0 = wt * __builtin_sqrtf(s0);
        v1 = wt * __builtin_sqrtf(s1);
        v2 = wt * __builtin_sqrtf(s2);
        v3 = wt * __builtin_sqrtf(s3);
    }
#pragma unroll
    for (int off = 32; off > 0; off >>= 1) {
        v0 += __shfl_down(v0, off, 64);
        v1 += __shfl_down(v1, off, 64);
        v2 += __shfl_down(v2, off, 64);
        v3 += __shfl_down(v3, off, 64);
    }
    __shared__ float wsum[2][4];
    if (g == 0 && w < 2) {
        wsum[w][0] = v0; wsum[w][1] = v1; wsum[w][2] = v2; wsum[w][3] = v3;
    }
    __syncthreads();
    if (tid < 4)                          // tile t=tid -> b = by + 8t
        ws[(by + 8 * tid) * GX + blockIdx.x] = wsum[0][tid] + wsum[1][tid];
}

__global__ __launch_bounds__(256) void reduce_kernel(
    const float* __restrict__ ws,  // [NBLK] = 2048
    float* __restrict__ out)       // [1]
{
    const int tid = threadIdx.x;
    float v = 0.f;
#pragma unroll
    for (int j = 0; j < NBLK / (256 * 4); ++j) {   // 2 float4 per thread
        const float4 p = *reinterpret_cast<const float4*>(ws + j * 1024 + tid * 4);
        v += p.x + p.y + p.z + p.w;
    }
#pragma unroll
    for (int off = 32; off > 0; off >>= 1) v += __shfl_down(v, off, 64);

    __shared__ float wsum[4];
    if ((tid & 63) == 0) wsum[tid >> 6] = v;
    __syncthreads();
    if (tid == 0)
        out[0] = (wsum[0] + wsum[1] + wsum[2] + wsum[3]) * (1.0f / (float)(B * N));
}

extern "C" void kernel_launch(void* const* d_in, const int* in_sizes, int n_in,
                              void* d_out, int out_size, void* d_ws, size_t ws_size,
                              hipStream_t stream) {
    const float* x = (const float*)d_in[0];
    const float* y = (const float*)d_in[1];
    float* out = (float*)d_out;
    float* ws  = (float*)d_ws;

    dim3 grid(GX, GY);             // (64, 8) = 512 blocks, 2/CU, 4 tiles each
    euclid_loss_kernel<<<grid, 256, 0, stream>>>(x, y, ws);
    reduce_kernel<<<1, 256, 0, stream>>>(ws, out);
}